// Round 16
// baseline (349.310 us; speedup 1.0000x reference)
//
#include <hip/hip_runtime.h>
#include <stdint.h>

// ---------------- problem constants ----------------
#define E_DIM   1024
#define H_NUM   16
#define HD      64        // head dim
#define F_DIM   4096
#define B_NUM   4
#define S_LEN   2048
#define M_ROWS  (B_NUM * S_LEN)   // 8192
#define QKV_LD  3072              // fused QKV row stride (elems)

typedef unsigned short u16;
typedef __bf16 bf16_t;
typedef bf16_t  bf16x8 __attribute__((ext_vector_type(8)));
typedef u16     u16x8  __attribute__((ext_vector_type(8)));
typedef float   f32x4  __attribute__((ext_vector_type(4)));
typedef float   f32x16 __attribute__((ext_vector_type(16)));
typedef unsigned u32x4 __attribute__((ext_vector_type(4)));

#define AS1 __attribute__((address_space(1)))
#define AS3 __attribute__((address_space(3)))

__device__ __forceinline__ void gload_lds16(const void* g, void* l) {
    __builtin_amdgcn_global_load_lds((AS1 void*)g, (AS3 void*)l, 16, 0, 0);
}

// f32 -> bf16 RNE
__device__ __forceinline__ u16 f2b(float f) {
    union { float f; unsigned u; } a; a.f = f;
    unsigned u = a.u + 0x7fffu + ((a.u >> 16) & 1u);
    return (u16)(u >> 16);
}
// bf16 (u16) -> f32
__device__ __forceinline__ float b2f(u16 v) {
    union { unsigned u; float f; } a; a.u = ((unsigned)v) << 16;
    return a.f;
}

__device__ __forceinline__ unsigned cvt_pk_bf16(float lo, float hi) {
    unsigned r;
    asm("v_cvt_pk_bf16_f32 %0, %1, %2" : "=v"(r) : "v"(lo), "v"(hi));
    return r;
}

// XOR swizzle for 128B-row LDS tiles (attn K tile; period 16 rows)
__device__ __forceinline__ int swz_c(int row) {
    return ((row & 7) << 4) ^ ((row & 8) << 2);
}
// XOR swizzle for 128B-row Vt tile (period 8 rows)
__device__ __forceinline__ int swz8(int row) {
    return (row & 7) << 4;
}

#define VM_WAIT(n) asm volatile("s_waitcnt vmcnt(" #n ")" ::: "memory")
#define SC_LOG2E 0.1803368801111204f   // 0.125 * log2(e)

// ---------------- fused cast kernel (x + all weights, 1 launch) ----------------
struct CastArgs {
    const float* src[7];
    u16* dst[7];
    float scale[7];
    unsigned cum4[8];   // prefix sums in float4 units
};

__global__ __launch_bounds__(256) void cast_multi(CastArgs a) {
    const int total = a.cum4[7];
    const int stride = gridDim.x * blockDim.x;
    for (int i = blockIdx.x * blockDim.x + threadIdx.x; i < total; i += stride) {
        int s = 0;
#pragma unroll
        for (int k = 1; k < 7; ++k) s += (i >= (int)a.cum4[k]);
        const int off = i - (int)a.cum4[s];
        const float sc = a.scale[s];
        float4 v = reinterpret_cast<const float4*>(a.src[s])[off];
        ushort4 o;
        o.x = f2b(v.x * sc); o.y = f2b(v.y * sc); o.z = f2b(v.z * sc); o.w = f2b(v.w * sc);
        reinterpret_cast<ushort4*>(a.dst[s])[off] = o;
    }
}

__device__ __forceinline__ void store_c(float* C, size_t idx, float v) { C[idx] = v; }
__device__ __forceinline__ void store_c(u16* C, size_t idx, float v)   { C[idx] = f2b(v); }

// ---------------- GEMM v2n: 256x128 tile, BK=32, 256 thr ----------------
// 4 waves (2M x 2N), per-wave 128x64. 3-buffer FIFO, prefetch-2, counted
// vmcnt, 1 barrier/K-step. 72KB LDS -> 2 blocks/CU.
// KSPAN: split-K via blockIdx.z; z-slice writes its own image C + z*M*N.
template <typename OutT, bool RELU, bool HASBIAS, int K, int KSPAN, bool VSPLIT>
__global__ __launch_bounds__(256, 2)
void gemm2n(const u16* __restrict__ A, const u16* __restrict__ B,
            OutT* __restrict__ C, const float* __restrict__ bias,
            char* __restrict__ VtG, int M, int N) {
    constexpr int NT = KSPAN / 32;
    __shared__ __align__(16) char smem[3 * 24576];

    const int tid  = threadIdx.x;
    const int lane = tid & 63, wave = tid >> 6;
    const int lr   = lane & 15, kh = lane >> 4;
    const int wr   = wave >> 1, wc = wave & 1;

    const int nwg = gridDim.x * gridDim.y;
    int wg = blockIdx.y * gridDim.x + blockIdx.x;
    const int cpx = nwg >> 3;
    wg = (wg & 7) * cpx + (wg >> 3);
    const int bx = wg % gridDim.x, by = wg / gridDim.x;
    const int row0 = by * 256, col0 = bx * 128;
    const int koff = blockIdx.z * KSPAN;

    const int srow = tid >> 2, scolb = (tid & 3) * 16;
    const char* Ag = (const char*)(A + (size_t)(row0 + srow) * K + koff) + scolb;
    const char* Bg = (const char*)(B + (size_t)(col0 + srow) * K + koff) + scolb;
    const size_t rstep = (size_t)64 * K * 2;
    OutT* Cz = C + (size_t)blockIdx.z * M * N;

    auto stage = [&](int t) {
        char* s = smem + (t % 3) * 24576;
        const size_t ko = (size_t)t * 64;
#pragma unroll
        for (int r = 0; r < 4; ++r)
            gload_lds16(Ag + r * rstep + ko, s + r * 4096 + tid * 16);
#pragma unroll
        for (int r = 0; r < 2; ++r)
            gload_lds16(Bg + r * rstep + ko, s + 16384 + r * 4096 + tid * 16);
    };

    f32x4 acc[8][4] = {};
    stage(0); stage(1);

    for (int t = 0; t < NT; ++t) {
        if (t + 1 < NT) VM_WAIT(6);
        else            VM_WAIT(0);
        __builtin_amdgcn_s_barrier();
        __builtin_amdgcn_sched_barrier(0);
        if (t + 2 < NT) stage(t + 2);

        const char* s = smem + (t % 3) * 24576;
        bf16x8 af[8], bf[4];
#pragma unroll
        for (int m = 0; m < 8; ++m)
            af[m] = *(const bf16x8*)(s + (wr * 128 + m * 16 + lr) * 64 + kh * 16);
#pragma unroll
        for (int n = 0; n < 4; ++n)
            bf[n] = *(const bf16x8*)(s + 16384 + (wc * 64 + n * 16 + lr) * 64 + kh * 16);

        __builtin_amdgcn_s_setprio(1);
#pragma unroll
        for (int m = 0; m < 8; ++m)
#pragma unroll
            for (int n = 0; n < 4; ++n)
                acc[m][n] = __builtin_amdgcn_mfma_f32_16x16x32_bf16(af[m], bf[n], acc[m][n], 0, 0, 0);
        __builtin_amdgcn_s_setprio(0);
    }

    if (VSPLIT && col0 >= 2048) {
#pragma unroll
        for (int m = 0; m < 8; ++m) {
#pragma unroll
            for (int n = 0; n < 4; ++n) {
                const int colv = col0 - 2048 + wc * 64 + n * 16 + lr;
                const int h = colv >> 6, d = colv & 63;
                const int rowq = row0 + wr * 128 + m * 16 + kh * 4;
                const int bq = rowq >> 11, sq = rowq & 2047;
                const int kvt = sq >> 6, kl = sq & 63;
                const int g = kl >> 4, qb = kl & 12;
                const int slotq = ((qb & 4) << 1) | ((qb & 8) >> 1) | (qb & 3);
                const size_t byte_off = ((size_t)((bq * H_NUM + h) * HD + d) << 12)
                                        + kvt * 128 + ((((g << 4) + slotq) << 1) ^ swz8(d));
                const u16 p0 = f2b(acc[m][n][0]), p1 = f2b(acc[m][n][1]);
                const u16 p2 = f2b(acc[m][n][2]), p3 = f2b(acc[m][n][3]);
                uint2 pk;
                pk.x = (unsigned)p0 | ((unsigned)p1 << 16);
                pk.y = (unsigned)p2 | ((unsigned)p3 << 16);
                *(uint2*)(VtG + byte_off) = pk;
            }
        }
        return;
    }

#pragma unroll
    for (int m = 0; m < 8; ++m) {
#pragma unroll
        for (int n = 0; n < 4; ++n) {
            int col = col0 + wc * 64 + n * 16 + lr;
            float bv = 0.f;
            if constexpr (HASBIAS) bv = bias[col];
#pragma unroll
            for (int r = 0; r < 4; ++r) {
                int row = row0 + wr * 128 + m * 16 + kh * 4 + r;
                float v = acc[m][n][r] + bv;
                if constexpr (RELU) v = fmaxf(v, 0.f);
                store_c(Cz, (size_t)row * N + col, v);
            }
        }
    }
}

// ---------------- flash attention, 32x32 swapped-QK, QBLK=256, KVBLK=64 ----------------
// 1D grid, bh-major: bid = q*64 + bh -> XCD = bh%8 (per-XCD L2-resident K/V).
// l via single ones-MFMA per half: pair-sum P slots in f32, then one mfma.
__global__ __launch_bounds__(512, 4)
void attn_kernel(const u16* __restrict__ QKV, const char* __restrict__ VtG,
                 u16* __restrict__ Ob) {
    __shared__ char Ks[2][64 * 128];   // [kv][d] swizzled, 8KB each
    __shared__ char Vt[2][64 * 128];   // [d][kv-permuted] swizzled, 8KB each

    const int tid  = threadIdx.x;
    const int lane = tid & 63, wave = tid >> 6;
    const int l31  = lane & 31, hi = lane >> 5;
    const int bid  = blockIdx.x;
    const int bh   = bid & 63;           // XCD = bid%8 = bh%8
    const int q0   = (bid >> 6) * 256;
    const int h    = bh & 15;
    const int b    = bh >> 4;

    const u16* Q  = QKV;
    const u16* Kp = QKV + 1024;

    const size_t qrow = (size_t)(b * S_LEN + q0 + wave * 32 + l31);
    bf16x8 qf[4];
#pragma unroll
    for (int c = 0; c < 4; ++c)
        qf[c] = *(const bf16x8*)(Q + qrow * QKV_LD + h * HD + c * 16 + hi * 8);

    bf16x8 ones;
#pragma unroll
    for (int j = 0; j < 8; ++j) ones[j] = (bf16_t)1.0f;

    f32x16 o0 = {}, o1 = {}, accl = {};

    const char* Kg  = (const char*)(Kp + (size_t)(b * S_LEN) * QKV_LD + h * HD);
    const char* Vgb = VtG + ((size_t)((b * H_NUM + h) * HD) << 12);   // [64 d][4096 B]

    const int ob      = wave * 1024 + lane * 16;
    const int st_row  = ob >> 7;
    const int st_colb = ob & 127;
    const int kst_colb = st_colb ^ swz_c(st_row);
    const int st_lds  = wave * 1024;
    const int krd = l31 * 128;
    const int vrd = l31 * 128;

    gload_lds16(Kg + (size_t)st_row * (QKV_LD * 2) + kst_colb, Ks[0] + st_lds);
    gload_lds16(Vgb + (size_t)st_row * 4096 + st_colb,         Vt[0] + st_lds);
    __syncthreads();

    const int NT = S_LEN / 64;   // 32
    for (int t = 0; t < NT; ++t) {
        const int cur = t & 1;
        if (t < NT - 1) {
            const int kv0n = (t + 1) * 64;
            gload_lds16(Kg + (size_t)(kv0n + st_row) * (QKV_LD * 2) + kst_colb,
                        Ks[cur ^ 1] + st_lds);
            gload_lds16(Vgb + (size_t)st_row * 4096 + (t + 1) * 128 + st_colb,
                        Vt[cur ^ 1] + st_lds);
        }

#pragma unroll
        for (int half = 0; half < 2; ++half) {
            const char* ksb = Ks[cur] + half * 4096 + krd;
            f32x16 st = {};
#pragma unroll
            for (int c = 0; c < 4; ++c) {
                bf16x8 kf = *(const bf16x8*)(ksb + ((c * 32 + hi * 16) ^ swz_c(l31)));
                st = __builtin_amdgcn_mfma_f32_32x32x16_bf16(kf, qf[c], st, 0, 0, 0);
            }

#pragma unroll
            for (int i = 0; i < 16; ++i)
                st[i] = __builtin_amdgcn_exp2f(st[i]);

            unsigned w[8];
#pragma unroll
            for (int i = 0; i < 8; ++i) w[i] = cvt_pk_bf16(st[2 * i], st[2 * i + 1]);

            // l: pair-sum slots (st[s] + st[8+s]) in f32, single ones-MFMA
            u32x4 fs;
#pragma unroll
            for (int i = 0; i < 4; ++i)
                fs[i] = cvt_pk_bf16(st[2 * i] + st[2 * i + 8], st[2 * i + 1] + st[2 * i + 9]);
            bf16x8 pfs = __builtin_bit_cast(bf16x8, fs);
            accl = __builtin_amdgcn_mfma_f32_32x32x16_bf16(ones, pfs, accl, 0, 0, 0);

#pragma unroll
            for (int cc = 0; cc < 2; ++cc) {
                u32x4 fw;
                fw[0] = w[4 * cc];     fw[1] = w[4 * cc + 1];
                fw[2] = w[4 * cc + 2]; fw[3] = w[4 * cc + 3];
                bf16x8 pf = __builtin_bit_cast(bf16x8, fw);
                const int colb = (half * 64 + cc * 32 + hi * 16) ^ swz8(l31);
                bf16x8 v0 = *(const bf16x8*)(Vt[cur] + vrd + colb);
                bf16x8 v1 = *(const bf16x8*)(Vt[cur] + 4096 + vrd + colb);
                o0 = __builtin_amdgcn_mfma_f32_32x32x16_bf16(v0, pf, o0, 0, 0, 0);
                o1 = __builtin_amdgcn_mfma_f32_32x32x16_bf16(v1, pf, o1, 0, 0, 0);
            }
        }
        __syncthreads();
    }

    const float inv = 1.0f / accl[0];
    unsigned m0[16], xx[16];
#pragma unroll
    for (int g = 0; g < 4; ++g)
#pragma unroll
        for (int u = 0; u < 2; ++u) {
            int r = g * 4 + 2 * u;
            m0[2 * g + u]     = cvt_pk_bf16(o0[r] * inv, o0[r + 1] * inv);
            m0[8 + 2 * g + u] = cvt_pk_bf16(o1[r] * inv, o1[r + 1] * inv);
        }
#pragma unroll
    for (int i = 0; i < 16; ++i) xx[i] = __shfl_xor(m0[i], 32);

    {
        unsigned full[8], sec[8];
#pragma unroll
        for (int g = 0; g < 4; ++g) {
            full[2 * g + 0] = hi ? xx[8 + 2 * g]     : m0[2 * g];
            full[2 * g + 1] = hi ? xx[8 + 2 * g + 1] : m0[2 * g + 1];
            sec[2 * g + 0]  = hi ? m0[8 + 2 * g]     : xx[2 * g];
            sec[2 * g + 1]  = hi ? m0[8 + 2 * g + 1] : xx[2 * g + 1];
        }
        u32x4 out0, out1, out2, out3;
        out0[0] = full[0]; out0[1] = full[1]; out0[2] = sec[0]; out0[3] = sec[1];
        out1[0] = full[2]; out1[1] = full[3]; out1[2] = sec[2]; out1[3] = sec[3];
        out2[0] = full[4]; out2[1] = full[5]; out2[2] = sec[4]; out2[3] = sec[5];
        out3[0] = full[6]; out3[1] = full[7]; out3[2] = sec[6]; out3[3] = sec[7];
        u16* op = Ob + qrow * E_DIM + h * HD + hi * 32;
        *(u32x4*)(op)      = out0;
        *(u32x4*)(op + 8)  = out1;
        *(u32x4*)(op + 16) = out2;
        *(u32x4*)(op + 24) = out3;
    }
}

// ---------------- fused residual add + LayerNorm ----------------
template <typename XA>
__device__ __forceinline__ float4 ld4(const XA* p, size_t idx) {
    if constexpr (sizeof(XA) == 2) {
        ushort4 v = reinterpret_cast<const ushort4*>(p)[idx];
        float4 o; o.x = b2f(v.x); o.y = b2f(v.y); o.z = b2f(v.z); o.w = b2f(v.w);
        return o;
    } else {
        return reinterpret_cast<const float4*>(p)[idx];
    }
}

// v = xa + p0 + p1 (+ bias); split-K reduce fused. Writes f32 of and/or bf16 ob.
template <bool HASB>
__global__ __launch_bounds__(256)
void add_ln_sk(const u16* __restrict__ xa, const u16* __restrict__ p0,
               const u16* __restrict__ p1, const float* __restrict__ bias,
               const float* __restrict__ g, const float* __restrict__ be,
               float* __restrict__ of, u16* __restrict__ ob) {
    const int row = blockIdx.x;
    const int t = threadIdx.x;
    const int lane = t & 63, wave = t >> 6;

    float4 va  = ld4<u16>(xa + (size_t)row * E_DIM, t);
    float4 vp0 = ld4<u16>(p0 + (size_t)row * E_DIM, t);
    float4 vp1 = ld4<u16>(p1 + (size_t)row * E_DIM, t);
    float v0 = va.x + vp0.x + vp1.x;
    float v1 = va.y + vp0.y + vp1.y;
    float v2 = va.z + vp0.z + vp1.z;
    float v3 = va.w + vp0.w + vp1.w;
    if constexpr (HASB) {
        float4 bi = reinterpret_cast<const float4*>(bias)[t];
        v0 += bi.x; v1 += bi.y; v2 += bi.z; v3 += bi.w;
    }
    float s  = v0 + v1 + v2 + v3;
    float s2 = v0 * v0 + v1 * v1 + v2 * v2 + v3 * v3;
#pragma unroll
    for (int m = 32; m >= 1; m >>= 1) {
        s  += __shfl_xor(s, m);
        s2 += __shfl_xor(s2, m);
    }
    __shared__ float red[8];
    if (lane == 0) { red[wave] = s; red[4 + wave] = s2; }
    __syncthreads();
    s  = red[0] + red[1] + red[2] + red[3];
    s2 = red[4] + red[5] + red[6] + red[7];

    float mu   = s * (1.0f / E_DIM);
    float var  = s2 * (1.0f / E_DIM) - mu * mu;
    float rstd = rsqrtf(var + 1e-5f);

    float4 gg = reinterpret_cast<const float4*>(g)[t];
    float4 bb = reinterpret_cast<const float4*>(be)[t];
    float y0 = (v0 - mu) * rstd * gg.x + bb.x;
    float y1 = (v1 - mu) * rstd * gg.y + bb.y;
    float y2 = (v2 - mu) * rstd * gg.z + bb.z;
    float y3 = (v3 - mu) * rstd * gg.w + bb.w;
    if (of) {
        float4 o; o.x = y0; o.y = y1; o.z = y2; o.w = y3;
        reinterpret_cast<float4*>(of + (size_t)row * E_DIM)[t] = o;
    }
    if (ob) {
        ushort4 o;
        o.x = f2b(y0); o.y = f2b(y1); o.z = f2b(y2); o.w = f2b(y3);
        reinterpret_cast<ushort4*>(ob + (size_t)row * E_DIM)[t] = o;
    }
}

// ---------------- launch ----------------
extern "C" void kernel_launch(void* const* d_in, const int* in_sizes, int n_in,
                              void* d_out, int out_size, void* d_ws, size_t ws_size,
                              hipStream_t stream) {
    const float* x   = (const float*)d_in[0];
    const float* Wq  = (const float*)d_in[1];
    const float* Wk  = (const float*)d_in[2];
    const float* Wv  = (const float*)d_in[3];
    const float* Wo  = (const float*)d_in[4];
    const float* g1  = (const float*)d_in[5];
    const float* b1  = (const float*)d_in[6];
    const float* g2  = (const float*)d_in[7];
    const float* b2  = (const float*)d_in[8];
    const float* W1  = (const float*)d_in[9];
    const float* bb1 = (const float*)d_in[10];
    const float* W2  = (const float*)d_in[11];
    const float* bb2 = (const float*)d_in[12];
    float* out = (float*)d_out;

    char* ws = (char*)d_ws;
    const size_t MB = 1024ull * 1024ull;
    u16* wqkvb = (u16*)(ws + 0 * MB);            // [3072,1024] bf16 = 6MB
    u16* wob   = (u16*)(ws + 6 * MB);
    u16* w1b   = (u16*)(ws + 8 * MB);
    u16* w2b   = (u16*)(ws + 16 * MB);
    u16* xb    = (u16*)(ws + 24 * MB);
    u16* qkvb  = (u16*)(ws + 40 * MB);           // [8192,3072] (V cols unused)
    u16* attnb = (u16*)(ws + 88 * MB);
    u16* hb    = (u16*)(ws + 136 * MB);
    char* VtG  = (ws + 152 * MB);                // [B*H][64 d][4096 B] = 16MB
    u16* ffn1  = (u16*)(ws + 24 * MB);           // reuse xb/qkvb region (after LN1)
    u16* psk   = (u16*)(ws + 104 * MB);          // split-K partials: 2 x 16MB

    dim3 blk(256);

    CastArgs ca;
    ca.src[0] = x;   ca.dst[0] = xb;                            ca.scale[0] = 1.f;
    ca.src[1] = Wq;  ca.dst[1] = wqkvb;                         ca.scale[1] = SC_LOG2E;
    ca.src[2] = Wk;  ca.dst[2] = wqkvb + E_DIM * E_DIM;         ca.scale[2] = 1.f;
    ca.src[3] = Wv;  ca.dst[3] = wqkvb + 2 * E_DIM * E_DIM;     ca.scale[3] = 1.f;
    ca.src[4] = Wo;  ca.dst[4] = wob;                           ca.scale[4] = 1.f;
    ca.src[5] = W1;  ca.dst[5] = w1b;                           ca.scale[5] = 1.f;
    ca.src[6] = W2;  ca.dst[6] = w2b;                           ca.scale[6] = 1.f;
    unsigned n4[7] = {M_ROWS * E_DIM / 4, E_DIM * E_DIM / 4, E_DIM * E_DIM / 4,
                      E_DIM * E_DIM / 4, E_DIM * E_DIM / 4, F_DIM * E_DIM / 4,
                      E_DIM * F_DIM / 4};
    ca.cum4[0] = 0;
    for (int i = 0; i < 7; ++i) ca.cum4[i + 1] = ca.cum4[i] + n4[i];
    cast_multi<<<dim3(2048), blk, 0, stream>>>(ca);

    // QKV fused: Q,K -> qkvb ; V -> VtG  (gemm2n: 256x128 tile, 768 blocks)
    gemm2n<u16, false, false, E_DIM, E_DIM, true><<<dim3(QKV_LD / 128, M_ROWS / 256), blk, 0, stream>>>(
        xb, wqkvb, qkvb, nullptr, VtG, M_ROWS, QKV_LD);

    // attn: 1D bh-major grid (512 blocks, 512 thr)
    attn_kernel<<<dim3(512), dim3(512), 0, stream>>>(qkvb, VtG, attnb);

    // Wo: [8192,1024] K=1024 split-K x2 on the gemm2n shape (512 blocks, 2/CU)
    gemm2n<u16, false, false, E_DIM, E_DIM / 2, false><<<dim3(E_DIM / 128, M_ROWS / 256, 2), blk, 0, stream>>>(
        attnb, wob, psk, nullptr, nullptr, M_ROWS, E_DIM);

    // LN1 with fused Wo split-K reduce (no bias); writes bf16 hb
    add_ln_sk<false><<<dim3(M_ROWS), blk, 0, stream>>>(
        xb, psk, psk + (size_t)M_ROWS * E_DIM, nullptr, g1, b1, nullptr, hb);

    // FFN1: [8192,4096]  (gemm2n, 1024 blocks)
    gemm2n<u16, true, true, E_DIM, E_DIM, false><<<dim3(F_DIM / 128, M_ROWS / 256), blk, 0, stream>>>(
        hb, w1b, ffn1, bb1, nullptr, M_ROWS, F_DIM);

    // FFN2: [8192,1024] K=4096 split-K x2 (512 blocks, 2/CU)
    gemm2n<u16, false, false, F_DIM, F_DIM / 2, false><<<dim3(E_DIM / 128, M_ROWS / 256, 2), blk, 0, stream>>>(
        ffn1, w2b, psk, nullptr, nullptr, M_ROWS, E_DIM);

    // LN2 with fused split-K reduce + bias; writes f32 out
    add_ln_sk<true><<<dim3(M_ROWS), blk, 0, stream>>>(
        hb, psk, psk + (size_t)M_ROWS * E_DIM, bb2, g2, b2, out, nullptr);
}

// Round 17
// 345.840 us; speedup vs baseline: 1.0100x; 1.0100x over previous
//
#include <hip/hip_runtime.h>
#include <stdint.h>

// ---------------- problem constants ----------------
#define E_DIM   1024
#define H_NUM   16
#define HD      64        // head dim
#define F_DIM   4096
#define B_NUM   4
#define S_LEN   2048
#define M_ROWS  (B_NUM * S_LEN)   // 8192
#define QKV_LD  3072              // fused QKV row stride (elems)

typedef unsigned short u16;
typedef __bf16 bf16_t;
typedef bf16_t  bf16x8 __attribute__((ext_vector_type(8)));
typedef u16     u16x8  __attribute__((ext_vector_type(8)));
typedef float   f32x4  __attribute__((ext_vector_type(4)));
typedef float   f32x16 __attribute__((ext_vector_type(16)));
typedef unsigned u32x4 __attribute__((ext_vector_type(4)));

#define AS1 __attribute__((address_space(1)))
#define AS3 __attribute__((address_space(3)))

__device__ __forceinline__ void gload_lds16(const void* g, void* l) {
    __builtin_amdgcn_global_load_lds((AS1 void*)g, (AS3 void*)l, 16, 0, 0);
}

// f32 -> bf16 RNE
__device__ __forceinline__ u16 f2b(float f) {
    union { float f; unsigned u; } a; a.f = f;
    unsigned u = a.u + 0x7fffu + ((a.u >> 16) & 1u);
    return (u16)(u >> 16);
}
// bf16 (u16) -> f32
__device__ __forceinline__ float b2f(u16 v) {
    union { unsigned u; float f; } a; a.u = ((unsigned)v) << 16;
    return a.f;
}

__device__ __forceinline__ unsigned cvt_pk_bf16(float lo, float hi) {
    unsigned r;
    asm("v_cvt_pk_bf16_f32 %0, %1, %2" : "=v"(r) : "v"(lo), "v"(hi));
    return r;
}

// XOR swizzle for 128B-row LDS tiles (attn K tile; period 16 rows)
__device__ __forceinline__ int swz_c(int row) {
    return ((row & 7) << 4) ^ ((row & 8) << 2);
}
// XOR swizzle for 128B-row Vt tile (period 8 rows)
__device__ __forceinline__ int swz8(int row) {
    return (row & 7) << 4;
}

#define VM_WAIT(n) asm volatile("s_waitcnt vmcnt(" #n ")" ::: "memory")
#define SC_LOG2E 0.1803368801111204f   // 0.125 * log2(e)

// ---------------- fused cast kernel (x + all weights, 1 launch) ----------------
struct CastArgs {
    const float* src[7];
    u16* dst[7];
    float scale[7];
    unsigned cum4[8];   // prefix sums in float4 units
};

__global__ __launch_bounds__(256) void cast_multi(CastArgs a) {
    const int total = a.cum4[7];
    const int stride = gridDim.x * blockDim.x;
    for (int i = blockIdx.x * blockDim.x + threadIdx.x; i < total; i += stride) {
        int s = 0;
#pragma unroll
        for (int k = 1; k < 7; ++k) s += (i >= (int)a.cum4[k]);
        const int off = i - (int)a.cum4[s];
        const float sc = a.scale[s];
        float4 v = reinterpret_cast<const float4*>(a.src[s])[off];
        ushort4 o;
        o.x = f2b(v.x * sc); o.y = f2b(v.y * sc); o.z = f2b(v.z * sc); o.w = f2b(v.w * sc);
        reinterpret_cast<ushort4*>(a.dst[s])[off] = o;
    }
}

__device__ __forceinline__ void store_c(float* C, size_t idx, float v) { C[idx] = v; }
__device__ __forceinline__ void store_c(u16* C, size_t idx, float v)   { C[idx] = f2b(v); }

// ---------------- GEMM v2n: 256x128 tile, BK=32, 256 thr ----------------
// 4 waves (2M x 2N), per-wave 128x64. 3-buffer FIFO, prefetch-2, counted
// vmcnt, 1 barrier/K-step. 72KB LDS -> 2 blocks/CU.
// KSPAN: split-K via blockIdx.z; z-slice writes its own image C + z*M*N.
template <typename OutT, bool RELU, bool HASBIAS, int K, int KSPAN, bool VSPLIT>
__global__ __launch_bounds__(256, 2)
void gemm2n(const u16* __restrict__ A, const u16* __restrict__ B,
            OutT* __restrict__ C, const float* __restrict__ bias,
            char* __restrict__ VtG, int M, int N) {
    constexpr int NT = KSPAN / 32;
    __shared__ __align__(16) char smem[3 * 24576];

    const int tid  = threadIdx.x;
    const int lane = tid & 63, wave = tid >> 6;
    const int lr   = lane & 15, kh = lane >> 4;
    const int wr   = wave >> 1, wc = wave & 1;

    const int nwg = gridDim.x * gridDim.y;
    int wg = blockIdx.y * gridDim.x + blockIdx.x;
    const int cpx = nwg >> 3;
    wg = (wg & 7) * cpx + (wg >> 3);
    const int bx = wg % gridDim.x, by = wg / gridDim.x;
    const int row0 = by * 256, col0 = bx * 128;
    const int koff = blockIdx.z * KSPAN;

    const int srow = tid >> 2, scolb = (tid & 3) * 16;
    const char* Ag = (const char*)(A + (size_t)(row0 + srow) * K + koff) + scolb;
    const char* Bg = (const char*)(B + (size_t)(col0 + srow) * K + koff) + scolb;
    const size_t rstep = (size_t)64 * K * 2;
    OutT* Cz = C + (size_t)blockIdx.z * M * N;

    auto stage = [&](int t) {
        char* s = smem + (t % 3) * 24576;
        const size_t ko = (size_t)t * 64;
#pragma unroll
        for (int r = 0; r < 4; ++r)
            gload_lds16(Ag + r * rstep + ko, s + r * 4096 + tid * 16);
#pragma unroll
        for (int r = 0; r < 2; ++r)
            gload_lds16(Bg + r * rstep + ko, s + 16384 + r * 4096 + tid * 16);
    };

    f32x4 acc[8][4] = {};
    stage(0); stage(1);

    for (int t = 0; t < NT; ++t) {
        if (t + 1 < NT) VM_WAIT(6);
        else            VM_WAIT(0);
        __builtin_amdgcn_s_barrier();
        __builtin_amdgcn_sched_barrier(0);
        if (t + 2 < NT) stage(t + 2);

        const char* s = smem + (t % 3) * 24576;
        bf16x8 af[8], bf[4];
#pragma unroll
        for (int m = 0; m < 8; ++m)
            af[m] = *(const bf16x8*)(s + (wr * 128 + m * 16 + lr) * 64 + kh * 16);
#pragma unroll
        for (int n = 0; n < 4; ++n)
            bf[n] = *(const bf16x8*)(s + 16384 + (wc * 64 + n * 16 + lr) * 64 + kh * 16);

        __builtin_amdgcn_s_setprio(1);
#pragma unroll
        for (int m = 0; m < 8; ++m)
#pragma unroll
            for (int n = 0; n < 4; ++n)
                acc[m][n] = __builtin_amdgcn_mfma_f32_16x16x32_bf16(af[m], bf[n], acc[m][n], 0, 0, 0);
        __builtin_amdgcn_s_setprio(0);
    }

    if (VSPLIT && col0 >= 2048) {
#pragma unroll
        for (int m = 0; m < 8; ++m) {
#pragma unroll
            for (int n = 0; n < 4; ++n) {
                const int colv = col0 - 2048 + wc * 64 + n * 16 + lr;
                const int h = colv >> 6, d = colv & 63;
                const int rowq = row0 + wr * 128 + m * 16 + kh * 4;
                const int bq = rowq >> 11, sq = rowq & 2047;
                const int kvt = sq >> 6, kl = sq & 63;
                const int g = kl >> 4, qb = kl & 12;
                const int slotq = ((qb & 4) << 1) | ((qb & 8) >> 1) | (qb & 3);
                const size_t byte_off = ((size_t)((bq * H_NUM + h) * HD + d) << 12)
                                        + kvt * 128 + ((((g << 4) + slotq) << 1) ^ swz8(d));
                const u16 p0 = f2b(acc[m][n][0]), p1 = f2b(acc[m][n][1]);
                const u16 p2 = f2b(acc[m][n][2]), p3 = f2b(acc[m][n][3]);
                uint2 pk;
                pk.x = (unsigned)p0 | ((unsigned)p1 << 16);
                pk.y = (unsigned)p2 | ((unsigned)p3 << 16);
                *(uint2*)(VtG + byte_off) = pk;
            }
        }
        return;
    }

#pragma unroll
    for (int m = 0; m < 8; ++m) {
#pragma unroll
        for (int n = 0; n < 4; ++n) {
            int col = col0 + wc * 64 + n * 16 + lr;
            float bv = 0.f;
            if constexpr (HASBIAS) bv = bias[col];
#pragma unroll
            for (int r = 0; r < 4; ++r) {
                int row = row0 + wr * 128 + m * 16 + kh * 4 + r;
                float v = acc[m][n][r] + bv;
                if constexpr (RELU) v = fmaxf(v, 0.f);
                store_c(Cz, (size_t)row * N + col, v);
            }
        }
    }
}

// ---------------- GEMM v2h: 128x128 tile, BK=32, 256 thr (Wo) ----------------
template <typename OutT, bool RELU, bool HASBIAS, int K>
__global__ __launch_bounds__(256, 3)
void gemm2h(const u16* __restrict__ A, const u16* __restrict__ B,
            OutT* __restrict__ C, const float* __restrict__ bias,
            int M, int N) {
    constexpr int NT = K / 32;
    __shared__ __align__(16) char smem[3 * 16384];

    const int tid  = threadIdx.x;
    const int lane = tid & 63, wave = tid >> 6;
    const int lr   = lane & 15, kh = lane >> 4;
    const int wr   = wave >> 1, wc = wave & 1;

    const int nwg = gridDim.x * gridDim.y;
    int wg = blockIdx.y * gridDim.x + blockIdx.x;
    const int cpx = nwg >> 3;
    wg = (wg & 7) * cpx + (wg >> 3);
    const int bx = wg % gridDim.x, by = wg / gridDim.x;
    const int row0 = by * 128, col0 = bx * 128;

    const int srow = tid >> 2;
    const int scolb = (tid & 3) * 16;
    const char* Ag = (const char*)(A + (size_t)(row0 + srow) * K) + scolb;
    const char* Bg = (const char*)(B + (size_t)(col0 + srow) * K) + scolb;
    const size_t rstep = (size_t)64 * K * 2;

    auto do_stage = [&](int t) {
        char* s = smem + (t % 3) * 16384;
        const size_t ko = (size_t)t * 64;
        gload_lds16(Ag + ko,         s + tid * 16);
        gload_lds16(Ag + rstep + ko, s + 4096 + tid * 16);
        gload_lds16(Bg + ko,         s + 8192 + tid * 16);
        gload_lds16(Bg + rstep + ko, s + 12288 + tid * 16);
    };

    f32x4 acc[4][4] = {};
    do_stage(0); do_stage(1);

    for (int t = 0; t < NT; ++t) {
        if (t + 1 < NT) VM_WAIT(4);
        else            VM_WAIT(0);
        __builtin_amdgcn_s_barrier();
        __builtin_amdgcn_sched_barrier(0);
        if (t + 2 < NT) do_stage(t + 2);

        const char* s = smem + (t % 3) * 16384;
        bf16x8 af[4], bf[4];
#pragma unroll
        for (int m = 0; m < 4; ++m)
            af[m] = *(const bf16x8*)(s + (wr * 64 + m * 16 + lr) * 64 + kh * 16);
#pragma unroll
        for (int n = 0; n < 4; ++n)
            bf[n] = *(const bf16x8*)(s + 8192 + (wc * 64 + n * 16 + lr) * 64 + kh * 16);

        __builtin_amdgcn_s_setprio(1);
#pragma unroll
        for (int m = 0; m < 4; ++m)
#pragma unroll
            for (int n = 0; n < 4; ++n)
                acc[m][n] = __builtin_amdgcn_mfma_f32_16x16x32_bf16(af[m], bf[n], acc[m][n], 0, 0, 0);
        __builtin_amdgcn_s_setprio(0);
    }

#pragma unroll
    for (int m = 0; m < 4; ++m) {
#pragma unroll
        for (int n = 0; n < 4; ++n) {
            int col = col0 + wc * 64 + n * 16 + lr;
            float bv = 0.f;
            if constexpr (HASBIAS) bv = bias[col];
#pragma unroll
            for (int r = 0; r < 4; ++r) {
                int row = row0 + wr * 64 + m * 16 + kh * 4 + r;
                float v = acc[m][n][r] + bv;
                if constexpr (RELU) v = fmaxf(v, 0.f);
                store_c(C, (size_t)row * N + col, v);
            }
        }
    }
}

// ---------------- flash attention, 32x32 swapped-QK, QBLK=256, KVBLK=64 ----------------
// 1D grid, bh-major: bid = q*64 + bh -> XCD = bh%8 (per-XCD L2-resident K/V).
// l via single ones-MFMA per half (pair-sum P slots in f32 first).
__global__ __launch_bounds__(512, 4)
void attn_kernel(const u16* __restrict__ QKV, const char* __restrict__ VtG,
                 u16* __restrict__ Ob) {
    __shared__ char Ks[2][64 * 128];   // [kv][d] swizzled, 8KB each
    __shared__ char Vt[2][64 * 128];   // [d][kv-permuted] swizzled, 8KB each

    const int tid  = threadIdx.x;
    const int lane = tid & 63, wave = tid >> 6;
    const int l31  = lane & 31, hi = lane >> 5;
    const int bid  = blockIdx.x;
    const int bh   = bid & 63;           // XCD = bid%8 = bh%8
    const int q0   = (bid >> 6) * 256;
    const int h    = bh & 15;
    const int b    = bh >> 4;

    const u16* Q  = QKV;
    const u16* Kp = QKV + 1024;

    const size_t qrow = (size_t)(b * S_LEN + q0 + wave * 32 + l31);
    bf16x8 qf[4];
#pragma unroll
    for (int c = 0; c < 4; ++c)
        qf[c] = *(const bf16x8*)(Q + qrow * QKV_LD + h * HD + c * 16 + hi * 8);

    bf16x8 ones;
#pragma unroll
    for (int j = 0; j < 8; ++j) ones[j] = (bf16_t)1.0f;

    f32x16 o0 = {}, o1 = {}, accl = {};

    const char* Kg  = (const char*)(Kp + (size_t)(b * S_LEN) * QKV_LD + h * HD);
    const char* Vgb = VtG + ((size_t)((b * H_NUM + h) * HD) << 12);   // [64 d][4096 B]

    const int ob      = wave * 1024 + lane * 16;
    const int st_row  = ob >> 7;
    const int st_colb = ob & 127;
    const int kst_colb = st_colb ^ swz_c(st_row);
    const int st_lds  = wave * 1024;
    const int krd = l31 * 128;
    const int vrd = l31 * 128;

    gload_lds16(Kg + (size_t)st_row * (QKV_LD * 2) + kst_colb, Ks[0] + st_lds);
    gload_lds16(Vgb + (size_t)st_row * 4096 + st_colb,         Vt[0] + st_lds);
    __syncthreads();

    const int NT = S_LEN / 64;   // 32
    for (int t = 0; t < NT; ++t) {
        const int cur = t & 1;
        if (t < NT - 1) {
            const int kv0n = (t + 1) * 64;
            gload_lds16(Kg + (size_t)(kv0n + st_row) * (QKV_LD * 2) + kst_colb,
                        Ks[cur ^ 1] + st_lds);
            gload_lds16(Vgb + (size_t)st_row * 4096 + (t + 1) * 128 + st_colb,
                        Vt[cur ^ 1] + st_lds);
        }

#pragma unroll
        for (int half = 0; half < 2; ++half) {
            const char* ksb = Ks[cur] + half * 4096 + krd;
            f32x16 st = {};
#pragma unroll
            for (int c = 0; c < 4; ++c) {
                bf16x8 kf = *(const bf16x8*)(ksb + ((c * 32 + hi * 16) ^ swz_c(l31)));
                st = __builtin_amdgcn_mfma_f32_32x32x16_bf16(kf, qf[c], st, 0, 0, 0);
            }

#pragma unroll
            for (int i = 0; i < 16; ++i)
                st[i] = __builtin_amdgcn_exp2f(st[i]);

            unsigned w[8];
#pragma unroll
            for (int i = 0; i < 8; ++i) w[i] = cvt_pk_bf16(st[2 * i], st[2 * i + 1]);

            // l: pair-sum slots (st[s] + st[8+s]) in f32, single ones-MFMA
            u32x4 fs;
#pragma unroll
            for (int i = 0; i < 4; ++i)
                fs[i] = cvt_pk_bf16(st[2 * i] + st[2 * i + 8], st[2 * i + 1] + st[2 * i + 9]);
            bf16x8 pfs = __builtin_bit_cast(bf16x8, fs);
            accl = __builtin_amdgcn_mfma_f32_32x32x16_bf16(ones, pfs, accl, 0, 0, 0);

#pragma unroll
            for (int cc = 0; cc < 2; ++cc) {
                u32x4 fw;
                fw[0] = w[4 * cc];     fw[1] = w[4 * cc + 1];
                fw[2] = w[4 * cc + 2]; fw[3] = w[4 * cc + 3];
                bf16x8 pf = __builtin_bit_cast(bf16x8, fw);
                const int colb = (half * 64 + cc * 32 + hi * 16) ^ swz8(l31);
                bf16x8 v0 = *(const bf16x8*)(Vt[cur] + vrd + colb);
                bf16x8 v1 = *(const bf16x8*)(Vt[cur] + 4096 + vrd + colb);
                o0 = __builtin_amdgcn_mfma_f32_32x32x16_bf16(v0, pf, o0, 0, 0, 0);
                o1 = __builtin_amdgcn_mfma_f32_32x32x16_bf16(v1, pf, o1, 0, 0, 0);
            }
        }
        __syncthreads();
    }

    const float inv = 1.0f / accl[0];
    unsigned m0[16], xx[16];
#pragma unroll
    for (int g = 0; g < 4; ++g)
#pragma unroll
        for (int u = 0; u < 2; ++u) {
            int r = g * 4 + 2 * u;
            m0[2 * g + u]     = cvt_pk_bf16(o0[r] * inv, o0[r + 1] * inv);
            m0[8 + 2 * g + u] = cvt_pk_bf16(o1[r] * inv, o1[r + 1] * inv);
        }
#pragma unroll
    for (int i = 0; i < 16; ++i) xx[i] = __shfl_xor(m0[i], 32);

    {
        unsigned full[8], sec[8];
#pragma unroll
        for (int g = 0; g < 4; ++g) {
            full[2 * g + 0] = hi ? xx[8 + 2 * g]     : m0[2 * g];
            full[2 * g + 1] = hi ? xx[8 + 2 * g + 1] : m0[2 * g + 1];
            sec[2 * g + 0]  = hi ? m0[8 + 2 * g]     : xx[2 * g];
            sec[2 * g + 1]  = hi ? m0[8 + 2 * g + 1] : xx[2 * g + 1];
        }
        u32x4 out0, out1, out2, out3;
        out0[0] = full[0]; out0[1] = full[1]; out0[2] = sec[0]; out0[3] = sec[1];
        out1[0] = full[2]; out1[1] = full[3]; out1[2] = sec[2]; out1[3] = sec[3];
        out2[0] = full[4]; out2[1] = full[5]; out2[2] = sec[4]; out2[3] = sec[5];
        out3[0] = full[6]; out3[1] = full[7]; out3[2] = sec[6]; out3[3] = sec[7];
        u16* op = Ob + qrow * E_DIM + h * HD + hi * 32;
        *(u32x4*)(op)      = out0;
        *(u32x4*)(op + 8)  = out1;
        *(u32x4*)(op + 16) = out2;
        *(u32x4*)(op + 24) = out3;
    }
}

// ---------------- fused residual add + LayerNorm ----------------
template <typename XA>
__device__ __forceinline__ float4 ld4(const XA* p, size_t idx) {
    if constexpr (sizeof(XA) == 2) {
        ushort4 v = reinterpret_cast<const ushort4*>(p)[idx];
        float4 o; o.x = b2f(v.x); o.y = b2f(v.y); o.z = b2f(v.z); o.w = b2f(v.w);
        return o;
    } else {
        return reinterpret_cast<const float4*>(p)[idx];
    }
}

template <typename XA, typename XB>
__global__ __launch_bounds__(256)
void add_ln(const XA* __restrict__ xa, const XB* __restrict__ xb2,
            const float* __restrict__ g, const float* __restrict__ be,
            float* __restrict__ of, u16* __restrict__ ob) {
    const int row = blockIdx.x;
    const int t = threadIdx.x;
    const int lane = t & 63, wave = t >> 6;

    float4 va = ld4<XA>(xa + (size_t)row * E_DIM, t);
    float4 vb = ld4<XB>(xb2 + (size_t)row * E_DIM, t);
    float v0 = va.x + vb.x, v1 = va.y + vb.y, v2 = va.z + vb.z, v3 = va.w + vb.w;
    float s  = v0 + v1 + v2 + v3;
    float s2 = v0 * v0 + v1 * v1 + v2 * v2 + v3 * v3;
#pragma unroll
    for (int m = 32; m >= 1; m >>= 1) {
        s  += __shfl_xor(s, m);
        s2 += __shfl_xor(s2, m);
    }
    __shared__ float red[8];
    if (lane == 0) { red[wave] = s; red[4 + wave] = s2; }
    __syncthreads();
    s  = red[0] + red[1] + red[2] + red[3];
    s2 = red[4] + red[5] + red[6] + red[7];

    float mu   = s * (1.0f / E_DIM);
    float var  = s2 * (1.0f / E_DIM) - mu * mu;
    float rstd = rsqrtf(var + 1e-5f);

    float4 gg = reinterpret_cast<const float4*>(g)[t];
    float4 bb = reinterpret_cast<const float4*>(be)[t];
    float y0 = (v0 - mu) * rstd * gg.x + bb.x;
    float y1 = (v1 - mu) * rstd * gg.y + bb.y;
    float y2 = (v2 - mu) * rstd * gg.z + bb.z;
    float y3 = (v3 - mu) * rstd * gg.w + bb.w;
    if (of) {
        float4 o; o.x = y0; o.y = y1; o.z = y2; o.w = y3;
        reinterpret_cast<float4*>(of + (size_t)row * E_DIM)[t] = o;
    }
    if (ob) {
        ushort4 o;
        o.x = f2b(y0); o.y = f2b(y1); o.z = f2b(y2); o.w = f2b(y3);
        reinterpret_cast<ushort4*>(ob + (size_t)row * E_DIM)[t] = o;
    }
}

// LN2 variant: v = hb + p0 + p1 + bias (split-K reduce fused), writes f32 out
__global__ __launch_bounds__(256)
void add_ln_sk(const u16* __restrict__ xa, const u16* __restrict__ p0,
               const u16* __restrict__ p1, const float* __restrict__ bias,
               const float* __restrict__ g, const float* __restrict__ be,
               float* __restrict__ of) {
    const int row = blockIdx.x;
    const int t = threadIdx.x;
    const int lane = t & 63, wave = t >> 6;

    float4 va  = ld4<u16>(xa + (size_t)row * E_DIM, t);
    float4 vp0 = ld4<u16>(p0 + (size_t)row * E_DIM, t);
    float4 vp1 = ld4<u16>(p1 + (size_t)row * E_DIM, t);
    float4 bi = reinterpret_cast<const float4*>(bias)[t];
    float v0 = va.x + vp0.x + vp1.x + bi.x;
    float v1 = va.y + vp0.y + vp1.y + bi.y;
    float v2 = va.z + vp0.z + vp1.z + bi.z;
    float v3 = va.w + vp0.w + vp1.w + bi.w;
    float s  = v0 + v1 + v2 + v3;
    float s2 = v0 * v0 + v1 * v1 + v2 * v2 + v3 * v3;
#pragma unroll
    for (int m = 32; m >= 1; m >>= 1) {
        s  += __shfl_xor(s, m);
        s2 += __shfl_xor(s2, m);
    }
    __shared__ float red[8];
    if (lane == 0) { red[wave] = s; red[4 + wave] = s2; }
    __syncthreads();
    s  = red[0] + red[1] + red[2] + red[3];
    s2 = red[4] + red[5] + red[6] + red[7];

    float mu   = s * (1.0f / E_DIM);
    float var  = s2 * (1.0f / E_DIM) - mu * mu;
    float rstd = rsqrtf(var + 1e-5f);

    float4 gg = reinterpret_cast<const float4*>(g)[t];
    float4 bb = reinterpret_cast<const float4*>(be)[t];
    float4 o;
    o.x = (v0 - mu) * rstd * gg.x + bb.x;
    o.y = (v1 - mu) * rstd * gg.y + bb.y;
    o.z = (v2 - mu) * rstd * gg.z + bb.z;
    o.w = (v3 - mu) * rstd * gg.w + bb.w;
    reinterpret_cast<float4*>(of + (size_t)row * E_DIM)[t] = o;
}

// ---------------- launch ----------------
extern "C" void kernel_launch(void* const* d_in, const int* in_sizes, int n_in,
                              void* d_out, int out_size, void* d_ws, size_t ws_size,
                              hipStream_t stream) {
    const float* x   = (const float*)d_in[0];
    const float* Wq  = (const float*)d_in[1];
    const float* Wk  = (const float*)d_in[2];
    const float* Wv  = (const float*)d_in[3];
    const float* Wo  = (const float*)d_in[4];
    const float* g1  = (const float*)d_in[5];
    const float* b1  = (const float*)d_in[6];
    const float* g2  = (const float*)d_in[7];
    const float* b2  = (const float*)d_in[8];
    const float* W1  = (const float*)d_in[9];
    const float* bb1 = (const float*)d_in[10];
    const float* W2  = (const float*)d_in[11];
    const float* bb2 = (const float*)d_in[12];
    float* out = (float*)d_out;

    char* ws = (char*)d_ws;
    const size_t MB = 1024ull * 1024ull;
    u16* wqkvb = (u16*)(ws + 0 * MB);            // [3072,1024] bf16 = 6MB
    u16* wob   = (u16*)(ws + 6 * MB);
    u16* w1b   = (u16*)(ws + 8 * MB);
    u16* w2b   = (u16*)(ws + 16 * MB);
    u16* xb    = (u16*)(ws + 24 * MB);
    u16* qkvb  = (u16*)(ws + 40 * MB);           // [8192,3072] (V cols unused)
    u16* attnb = (u16*)(ws + 88 * MB);
    u16* attno = (u16*)(ws + 104 * MB);
    u16* hb    = (u16*)(ws + 136 * MB);
    char* VtG  = (ws + 152 * MB);                // [B*H][64 d][4096 B] = 16MB
    u16* ffn1  = (u16*)(ws + 24 * MB);           // reuse xb/qkvb region (after LN1)
    u16* psk   = (u16*)(ws + 168 * MB);          // FFN2 split-K partials: 2 x 16MB

    dim3 blk(256);

    CastArgs ca;
    ca.src[0] = x;   ca.dst[0] = xb;                            ca.scale[0] = 1.f;
    ca.src[1] = Wq;  ca.dst[1] = wqkvb;                         ca.scale[1] = SC_LOG2E;
    ca.src[2] = Wk;  ca.dst[2] = wqkvb + E_DIM * E_DIM;         ca.scale[2] = 1.f;
    ca.src[3] = Wv;  ca.dst[3] = wqkvb + 2 * E_DIM * E_DIM;     ca.scale[3] = 1.f;
    ca.src[4] = Wo;  ca.dst[4] = wob;                           ca.scale[4] = 1.f;
    ca.src[5] = W1;  ca.dst[5] = w1b;                           ca.scale[5] = 1.f;
    ca.src[6] = W2;  ca.dst[6] = w2b;                           ca.scale[6] = 1.f;
    unsigned n4[7] = {M_ROWS * E_DIM / 4, E_DIM * E_DIM / 4, E_DIM * E_DIM / 4,
                      E_DIM * E_DIM / 4, E_DIM * E_DIM / 4, F_DIM * E_DIM / 4,
                      E_DIM * F_DIM / 4};
    ca.cum4[0] = 0;
    for (int i = 0; i < 7; ++i) ca.cum4[i + 1] = ca.cum4[i] + n4[i];
    cast_multi<<<dim3(2048), blk, 0, stream>>>(ca);

    // QKV fused: Q,K -> qkvb ; V -> VtG  (gemm2n: 256x128 tile, 768 blocks)
    gemm2n<u16, false, false, E_DIM, E_DIM, true><<<dim3(QKV_LD / 128, M_ROWS / 256), blk, 0, stream>>>(
        xb, wqkvb, qkvb, nullptr, VtG, M_ROWS, QKV_LD);

    // attn: 1D bh-major grid (512 blocks, 512 thr)
    attn_kernel<<<dim3(512), dim3(512), 0, stream>>>(qkvb, VtG, attnb);

    // Wo: [8192,1024] on gemm2h (R15's split-K variant was net-negative)
    gemm2h<u16, false, false, E_DIM><<<dim3(E_DIM / 128, M_ROWS / 128), blk, 0, stream>>>(
        attnb, wob, attno, nullptr, M_ROWS, E_DIM);

    // LN1: residual uses bf16 x (xb)
    add_ln<u16, u16><<<dim3(M_ROWS), blk, 0, stream>>>(xb, attno, g1, b1, nullptr, hb);

    // FFN1: [8192,4096]  (gemm2n, 1024 blocks)
    gemm2n<u16, true, true, E_DIM, E_DIM, false><<<dim3(F_DIM / 128, M_ROWS / 256), blk, 0, stream>>>(
        hb, w1b, ffn1, bb1, nullptr, M_ROWS, F_DIM);

    // FFN2: [8192,1024] K=4096 split-K x2 (512 blocks, 2/CU)
    gemm2n<u16, false, false, F_DIM, F_DIM / 2, false><<<dim3(E_DIM / 128, M_ROWS / 256, 2), blk, 0, stream>>>(
        ffn1, w2b, psk, nullptr, nullptr, M_ROWS, E_DIM);

    // LN2 with fused split-K reduce + bias
    add_ln_sk<<<dim3(M_ROWS), blk, 0, stream>>>(
        hb, psk, psk + (size_t)M_ROWS * E_DIM, bb2, g2, b2, out);
}

// Round 18
// 345.477 us; speedup vs baseline: 1.0111x; 1.0011x over previous
//
#include <hip/hip_runtime.h>
#include <stdint.h>

// ---------------- problem constants ----------------
#define E_DIM   1024
#define H_NUM   16
#define HD      64        // head dim
#define F_DIM   4096
#define B_NUM   4
#define S_LEN   2048
#define M_ROWS  (B_NUM * S_LEN)   // 8192
#define QKV_LD  3072              // fused QKV row stride (elems)

typedef unsigned short u16;
typedef __bf16 bf16_t;
typedef bf16_t  bf16x8 __attribute__((ext_vector_type(8)));
typedef u16     u16x8  __attribute__((ext_vector_type(8)));
typedef float   f32x4  __attribute__((ext_vector_type(4)));
typedef float   f32x16 __attribute__((ext_vector_type(16)));
typedef unsigned u32x4 __attribute__((ext_vector_type(4)));

#define AS1 __attribute__((address_space(1)))
#define AS3 __attribute__((address_space(3)))

__device__ __forceinline__ void gload_lds16(const void* g, void* l) {
    __builtin_amdgcn_global_load_lds((AS1 void*)g, (AS3 void*)l, 16, 0, 0);
}

// f32 -> bf16 RNE
__device__ __forceinline__ u16 f2b(float f) {
    union { float f; unsigned u; } a; a.f = f;
    unsigned u = a.u + 0x7fffu + ((a.u >> 16) & 1u);
    return (u16)(u >> 16);
}
// bf16 (u16) -> f32
__device__ __forceinline__ float b2f(u16 v) {
    union { unsigned u; float f; } a; a.u = ((unsigned)v) << 16;
    return a.f;
}

__device__ __forceinline__ unsigned cvt_pk_bf16(float lo, float hi) {
    unsigned r;
    asm("v_cvt_pk_bf16_f32 %0, %1, %2" : "=v"(r) : "v"(lo), "v"(hi));
    return r;
}

// XOR swizzle for 128B-row LDS tiles (attn K tile; period 16 rows)
__device__ __forceinline__ int swz_c(int row) {
    return ((row & 7) << 4) ^ ((row & 8) << 2);
}
// XOR swizzle for 128B-row Vt tile (period 8 rows)
__device__ __forceinline__ int swz8(int row) {
    return (row & 7) << 4;
}

#define VM_WAIT(n) asm volatile("s_waitcnt vmcnt(" #n ")" ::: "memory")
#define SC_LOG2E 0.1803368801111204f   // 0.125 * log2(e)

// ---------------- fused cast kernel (x + all weights, 1 launch) ----------------
struct CastArgs {
    const float* src[7];
    u16* dst[7];
    float scale[7];
    unsigned cum4[8];   // prefix sums in float4 units
};

__global__ __launch_bounds__(256) void cast_multi(CastArgs a) {
    const int total = a.cum4[7];
    const int stride = gridDim.x * blockDim.x;
    for (int i = blockIdx.x * blockDim.x + threadIdx.x; i < total; i += stride) {
        int s = 0;
#pragma unroll
        for (int k = 1; k < 7; ++k) s += (i >= (int)a.cum4[k]);
        const int off = i - (int)a.cum4[s];
        const float sc = a.scale[s];
        float4 v = reinterpret_cast<const float4*>(a.src[s])[off];
        ushort4 o;
        o.x = f2b(v.x * sc); o.y = f2b(v.y * sc); o.z = f2b(v.z * sc); o.w = f2b(v.w * sc);
        reinterpret_cast<ushort4*>(a.dst[s])[off] = o;
    }
}

__device__ __forceinline__ void store_c(float* C, size_t idx, float v) { C[idx] = v; }
__device__ __forceinline__ void store_c(u16* C, size_t idx, float v)   { C[idx] = f2b(v); }

// ---------------- GEMM v2n: 256x128 tile, BK=32, 256 thr ----------------
// 4 waves (2M x 2N), per-wave 128x64. 3-buffer FIFO, prefetch-2, counted
// vmcnt, 1 barrier/K-step. 72KB LDS -> 2 blocks/CU.
// KSPAN: split-K via blockIdx.z; z-slice writes its own image C + z*M*N.
template <typename OutT, bool RELU, bool HASBIAS, int K, int KSPAN, bool VSPLIT>
__global__ __launch_bounds__(256, 2)
void gemm2n(const u16* __restrict__ A, const u16* __restrict__ B,
            OutT* __restrict__ C, const float* __restrict__ bias,
            char* __restrict__ VtG, int M, int N) {
    constexpr int NT = KSPAN / 32;
    __shared__ __align__(16) char smem[3 * 24576];

    const int tid  = threadIdx.x;
    const int lane = tid & 63, wave = tid >> 6;
    const int lr   = lane & 15, kh = lane >> 4;
    const int wr   = wave >> 1, wc = wave & 1;

    const int nwg = gridDim.x * gridDim.y;
    int wg = blockIdx.y * gridDim.x + blockIdx.x;
    const int cpx = nwg >> 3;
    wg = (wg & 7) * cpx + (wg >> 3);
    const int bx = wg % gridDim.x, by = wg / gridDim.x;
    const int row0 = by * 256, col0 = bx * 128;
    const int koff = blockIdx.z * KSPAN;

    const int srow = tid >> 2, scolb = (tid & 3) * 16;
    const char* Ag = (const char*)(A + (size_t)(row0 + srow) * K + koff) + scolb;
    const char* Bg = (const char*)(B + (size_t)(col0 + srow) * K + koff) + scolb;
    const size_t rstep = (size_t)64 * K * 2;
    OutT* Cz = C + (size_t)blockIdx.z * M * N;

    auto stage = [&](int t) {
        char* s = smem + (t % 3) * 24576;
        const size_t ko = (size_t)t * 64;
#pragma unroll
        for (int r = 0; r < 4; ++r)
            gload_lds16(Ag + r * rstep + ko, s + r * 4096 + tid * 16);
#pragma unroll
        for (int r = 0; r < 2; ++r)
            gload_lds16(Bg + r * rstep + ko, s + 16384 + r * 4096 + tid * 16);
    };

    f32x4 acc[8][4] = {};
    stage(0); stage(1);

    for (int t = 0; t < NT; ++t) {
        if (t + 1 < NT) VM_WAIT(6);
        else            VM_WAIT(0);
        __builtin_amdgcn_s_barrier();
        __builtin_amdgcn_sched_barrier(0);
        if (t + 2 < NT) stage(t + 2);

        const char* s = smem + (t % 3) * 24576;
        bf16x8 af[8], bf[4];
#pragma unroll
        for (int m = 0; m < 8; ++m)
            af[m] = *(const bf16x8*)(s + (wr * 128 + m * 16 + lr) * 64 + kh * 16);
#pragma unroll
        for (int n = 0; n < 4; ++n)
            bf[n] = *(const bf16x8*)(s + 16384 + (wc * 64 + n * 16 + lr) * 64 + kh * 16);

        __builtin_amdgcn_s_setprio(1);
#pragma unroll
        for (int m = 0; m < 8; ++m)
#pragma unroll
            for (int n = 0; n < 4; ++n)
                acc[m][n] = __builtin_amdgcn_mfma_f32_16x16x32_bf16(af[m], bf[n], acc[m][n], 0, 0, 0);
        __builtin_amdgcn_s_setprio(0);
    }

    if (VSPLIT && col0 >= 2048) {
#pragma unroll
        for (int m = 0; m < 8; ++m) {
#pragma unroll
            for (int n = 0; n < 4; ++n) {
                const int colv = col0 - 2048 + wc * 64 + n * 16 + lr;
                const int h = colv >> 6, d = colv & 63;
                const int rowq = row0 + wr * 128 + m * 16 + kh * 4;
                const int bq = rowq >> 11, sq = rowq & 2047;
                const int kvt = sq >> 6, kl = sq & 63;
                const int g = kl >> 4, qb = kl & 12;
                const int slotq = ((qb & 4) << 1) | ((qb & 8) >> 1) | (qb & 3);
                const size_t byte_off = ((size_t)((bq * H_NUM + h) * HD + d) << 12)
                                        + kvt * 128 + ((((g << 4) + slotq) << 1) ^ swz8(d));
                const u16 p0 = f2b(acc[m][n][0]), p1 = f2b(acc[m][n][1]);
                const u16 p2 = f2b(acc[m][n][2]), p3 = f2b(acc[m][n][3]);
                uint2 pk;
                pk.x = (unsigned)p0 | ((unsigned)p1 << 16);
                pk.y = (unsigned)p2 | ((unsigned)p3 << 16);
                *(uint2*)(VtG + byte_off) = pk;
            }
        }
        return;
    }

#pragma unroll
    for (int m = 0; m < 8; ++m) {
#pragma unroll
        for (int n = 0; n < 4; ++n) {
            int col = col0 + wc * 64 + n * 16 + lr;
            float bv = 0.f;
            if constexpr (HASBIAS) bv = bias[col];
#pragma unroll
            for (int r = 0; r < 4; ++r) {
                int row = row0 + wr * 128 + m * 16 + kh * 4 + r;
                float v = acc[m][n][r] + bv;
                if constexpr (RELU) v = fmaxf(v, 0.f);
                store_c(Cz, (size_t)row * N + col, v);
            }
        }
    }
}

// ---------------- GEMM v2h: 128x128 tile, BK=32, 256 thr (Wo) ----------------
template <typename OutT, bool RELU, bool HASBIAS, int K>
__global__ __launch_bounds__(256, 3)
void gemm2h(const u16* __restrict__ A, const u16* __restrict__ B,
            OutT* __restrict__ C, const float* __restrict__ bias,
            int M, int N) {
    constexpr int NT = K / 32;
    __shared__ __align__(16) char smem[3 * 16384];

    const int tid  = threadIdx.x;
    const int lane = tid & 63, wave = tid >> 6;
    const int lr   = lane & 15, kh = lane >> 4;
    const int wr   = wave >> 1, wc = wave & 1;

    const int nwg = gridDim.x * gridDim.y;
    int wg = blockIdx.y * gridDim.x + blockIdx.x;
    const int cpx = nwg >> 3;
    wg = (wg & 7) * cpx + (wg >> 3);
    const int bx = wg % gridDim.x, by = wg / gridDim.x;
    const int row0 = by * 128, col0 = bx * 128;

    const int srow = tid >> 2;
    const int scolb = (tid & 3) * 16;
    const char* Ag = (const char*)(A + (size_t)(row0 + srow) * K) + scolb;
    const char* Bg = (const char*)(B + (size_t)(col0 + srow) * K) + scolb;
    const size_t rstep = (size_t)64 * K * 2;

    auto do_stage = [&](int t) {
        char* s = smem + (t % 3) * 16384;
        const size_t ko = (size_t)t * 64;
        gload_lds16(Ag + ko,         s + tid * 16);
        gload_lds16(Ag + rstep + ko, s + 4096 + tid * 16);
        gload_lds16(Bg + ko,         s + 8192 + tid * 16);
        gload_lds16(Bg + rstep + ko, s + 12288 + tid * 16);
    };

    f32x4 acc[4][4] = {};
    do_stage(0); do_stage(1);

    for (int t = 0; t < NT; ++t) {
        if (t + 1 < NT) VM_WAIT(4);
        else            VM_WAIT(0);
        __builtin_amdgcn_s_barrier();
        __builtin_amdgcn_sched_barrier(0);
        if (t + 2 < NT) do_stage(t + 2);

        const char* s = smem + (t % 3) * 16384;
        bf16x8 af[4], bf[4];
#pragma unroll
        for (int m = 0; m < 4; ++m)
            af[m] = *(const bf16x8*)(s + (wr * 64 + m * 16 + lr) * 64 + kh * 16);
#pragma unroll
        for (int n = 0; n < 4; ++n)
            bf[n] = *(const bf16x8*)(s + 8192 + (wc * 64 + n * 16 + lr) * 64 + kh * 16);

        __builtin_amdgcn_s_setprio(1);
#pragma unroll
        for (int m = 0; m < 4; ++m)
#pragma unroll
            for (int n = 0; n < 4; ++n)
                acc[m][n] = __builtin_amdgcn_mfma_f32_16x16x32_bf16(af[m], bf[n], acc[m][n], 0, 0, 0);
        __builtin_amdgcn_s_setprio(0);
    }

#pragma unroll
    for (int m = 0; m < 4; ++m) {
#pragma unroll
        for (int n = 0; n < 4; ++n) {
            int col = col0 + wc * 64 + n * 16 + lr;
            float bv = 0.f;
            if constexpr (HASBIAS) bv = bias[col];
#pragma unroll
            for (int r = 0; r < 4; ++r) {
                int row = row0 + wr * 64 + m * 16 + kh * 4 + r;
                float v = acc[m][n][r] + bv;
                if constexpr (RELU) v = fmaxf(v, 0.f);
                store_c(C, (size_t)row * N + col, v);
            }
        }
    }
}

// ---------------- flash attention: 32x32 swapped-QK, QBLK=256, paired KV tiles ----------------
// 1D grid, bh-major: XCD = bh%8 (per-XCD L2-resident K/V). Two 64-kv sub-tiles
// processed per barrier (32 -> 16 barriers); per-sub-tile layout identical to
// the proven single-tile code. l via single ones-MFMA per 32-kv half.
__global__ __launch_bounds__(512, 4)
void attn_kernel(const u16* __restrict__ QKV, const char* __restrict__ VtG,
                 u16* __restrict__ Ob) {
    __shared__ char Ks[2][2][64 * 128];   // [pair][sub][kv][d] swizzled, 8KB each
    __shared__ char Vt[2][2][64 * 128];   // [pair][sub][d][kv-permuted] swizzled

    const int tid  = threadIdx.x;
    const int lane = tid & 63, wave = tid >> 6;
    const int l31  = lane & 31, hi = lane >> 5;
    const int bid  = blockIdx.x;
    const int bh   = bid & 63;           // XCD = bid%8 = bh%8
    const int q0   = (bid >> 6) * 256;
    const int h    = bh & 15;
    const int b    = bh >> 4;

    const u16* Q  = QKV;
    const u16* Kp = QKV + 1024;

    const size_t qrow = (size_t)(b * S_LEN + q0 + wave * 32 + l31);
    bf16x8 qf[4];
#pragma unroll
    for (int c = 0; c < 4; ++c)
        qf[c] = *(const bf16x8*)(Q + qrow * QKV_LD + h * HD + c * 16 + hi * 8);

    bf16x8 ones;
#pragma unroll
    for (int j = 0; j < 8; ++j) ones[j] = (bf16_t)1.0f;

    f32x16 o0 = {}, o1 = {}, accl = {};

    const char* Kg  = (const char*)(Kp + (size_t)(b * S_LEN) * QKV_LD + h * HD);
    const char* Vgb = VtG + ((size_t)((b * H_NUM + h) * HD) << 12);   // [64 d][4096 B]

    const int ob      = wave * 1024 + lane * 16;
    const int st_row  = ob >> 7;
    const int st_colb = ob & 127;
    const int kst_colb = st_colb ^ swz_c(st_row);
    const int st_lds  = wave * 1024;
    const int krd = l31 * 128;
    const int vrd = l31 * 128;

    // ---- prologue: stage pair 0 (sub-tiles 0,1; K + V each)
#pragma unroll
    for (int sub = 0; sub < 2; ++sub) {
        gload_lds16(Kg + (size_t)(sub * 64 + st_row) * (QKV_LD * 2) + kst_colb,
                    Ks[0][sub] + st_lds);
        gload_lds16(Vgb + (size_t)st_row * 4096 + sub * 128 + st_colb,
                    Vt[0][sub] + st_lds);
    }
    __syncthreads();

    const int NT = S_LEN / 128;   // 16 pair-iterations
    for (int t = 0; t < NT; ++t) {
        const int cur = t & 1;
        if (t < NT - 1) {
#pragma unroll
            for (int sub = 0; sub < 2; ++sub) {
                const int tt = 2 * (t + 1) + sub;   // 64-kv tile index
                gload_lds16(Kg + (size_t)(tt * 64 + st_row) * (QKV_LD * 2) + kst_colb,
                            Ks[cur ^ 1][sub] + st_lds);
                gload_lds16(Vgb + (size_t)st_row * 4096 + tt * 128 + st_colb,
                            Vt[cur ^ 1][sub] + st_lds);
            }
        }

#pragma unroll
        for (int sub = 0; sub < 2; ++sub) {
#pragma unroll
            for (int half = 0; half < 2; ++half) {
                const char* ksb = Ks[cur][sub] + half * 4096 + krd;
                f32x16 st = {};
#pragma unroll
                for (int c = 0; c < 4; ++c) {
                    bf16x8 kf = *(const bf16x8*)(ksb + ((c * 32 + hi * 16) ^ swz_c(l31)));
                    st = __builtin_amdgcn_mfma_f32_32x32x16_bf16(kf, qf[c], st, 0, 0, 0);
                }

#pragma unroll
                for (int i = 0; i < 16; ++i)
                    st[i] = __builtin_amdgcn_exp2f(st[i]);

                unsigned w[8];
#pragma unroll
                for (int i = 0; i < 8; ++i) w[i] = cvt_pk_bf16(st[2 * i], st[2 * i + 1]);

                // l: pair-sum slots (st[s] + st[8+s]) in f32, single ones-MFMA
                u32x4 fs;
#pragma unroll
                for (int i = 0; i < 4; ++i)
                    fs[i] = cvt_pk_bf16(st[2 * i] + st[2 * i + 8], st[2 * i + 1] + st[2 * i + 9]);
                bf16x8 pfs = __builtin_bit_cast(bf16x8, fs);
                accl = __builtin_amdgcn_mfma_f32_32x32x16_bf16(ones, pfs, accl, 0, 0, 0);

#pragma unroll
                for (int cc = 0; cc < 2; ++cc) {
                    u32x4 fw;
                    fw[0] = w[4 * cc];     fw[1] = w[4 * cc + 1];
                    fw[2] = w[4 * cc + 2]; fw[3] = w[4 * cc + 3];
                    bf16x8 pf = __builtin_bit_cast(bf16x8, fw);
                    const int colb = (half * 64 + cc * 32 + hi * 16) ^ swz8(l31);
                    bf16x8 v0 = *(const bf16x8*)(Vt[cur][sub] + vrd + colb);
                    bf16x8 v1 = *(const bf16x8*)(Vt[cur][sub] + 4096 + vrd + colb);
                    o0 = __builtin_amdgcn_mfma_f32_32x32x16_bf16(v0, pf, o0, 0, 0, 0);
                    o1 = __builtin_amdgcn_mfma_f32_32x32x16_bf16(v1, pf, o1, 0, 0, 0);
                }
            }
        }
        __syncthreads();
    }

    const float inv = 1.0f / accl[0];
    unsigned m0[16], xx[16];
#pragma unroll
    for (int g = 0; g < 4; ++g)
#pragma unroll
        for (int u = 0; u < 2; ++u) {
            int r = g * 4 + 2 * u;
            m0[2 * g + u]     = cvt_pk_bf16(o0[r] * inv, o0[r + 1] * inv);
            m0[8 + 2 * g + u] = cvt_pk_bf16(o1[r] * inv, o1[r + 1] * inv);
        }
#pragma unroll
    for (int i = 0; i < 16; ++i) xx[i] = __shfl_xor(m0[i], 32);

    {
        unsigned full[8], sec[8];
#pragma unroll
        for (int g = 0; g < 4; ++g) {
            full[2 * g + 0] = hi ? xx[8 + 2 * g]     : m0[2 * g];
            full[2 * g + 1] = hi ? xx[8 + 2 * g + 1] : m0[2 * g + 1];
            sec[2 * g + 0]  = hi ? m0[8 + 2 * g]     : xx[2 * g];
            sec[2 * g + 1]  = hi ? m0[8 + 2 * g + 1] : xx[2 * g + 1];
        }
        u32x4 out0, out1, out2, out3;
        out0[0] = full[0]; out0[1] = full[1]; out0[2] = sec[0]; out0[3] = sec[1];
        out1[0] = full[2]; out1[1] = full[3]; out1[2] = sec[2]; out1[3] = sec[3];
        out2[0] = full[4]; out2[1] = full[5]; out2[2] = sec[4]; out2[3] = sec[5];
        out3[0] = full[6]; out3[1] = full[7]; out3[2] = sec[6]; out3[3] = sec[7];
        u16* op = Ob + qrow * E_DIM + h * HD + hi * 32;
        *(u32x4*)(op)      = out0;
        *(u32x4*)(op + 8)  = out1;
        *(u32x4*)(op + 16) = out2;
        *(u32x4*)(op + 24) = out3;
    }
}

// ---------------- fused residual add + LayerNorm ----------------
template <typename XA>
__device__ __forceinline__ float4 ld4(const XA* p, size_t idx) {
    if constexpr (sizeof(XA) == 2) {
        ushort4 v = reinterpret_cast<const ushort4*>(p)[idx];
        float4 o; o.x = b2f(v.x); o.y = b2f(v.y); o.z = b2f(v.z); o.w = b2f(v.w);
        return o;
    } else {
        return reinterpret_cast<const float4*>(p)[idx];
    }
}

template <typename XA, typename XB>
__global__ __launch_bounds__(256)
void add_ln(const XA* __restrict__ xa, const XB* __restrict__ xb2,
            const float* __restrict__ g, const float* __restrict__ be,
            float* __restrict__ of, u16* __restrict__ ob) {
    const int row = blockIdx.x;
    const int t = threadIdx.x;
    const int lane = t & 63, wave = t >> 6;

    float4 va = ld4<XA>(xa + (size_t)row * E_DIM, t);
    float4 vb = ld4<XB>(xb2 + (size_t)row * E_DIM, t);
    float v0 = va.x + vb.x, v1 = va.y + vb.y, v2 = va.z + vb.z, v3 = va.w + vb.w;
    float s  = v0 + v1 + v2 + v3;
    float s2 = v0 * v0 + v1 * v1 + v2 * v2 + v3 * v3;
#pragma unroll
    for (int m = 32; m >= 1; m >>= 1) {
        s  += __shfl_xor(s, m);
        s2 += __shfl_xor(s2, m);
    }
    __shared__ float red[8];
    if (lane == 0) { red[wave] = s; red[4 + wave] = s2; }
    __syncthreads();
    s  = red[0] + red[1] + red[2] + red[3];
    s2 = red[4] + red[5] + red[6] + red[7];

    float mu   = s * (1.0f / E_DIM);
    float var  = s2 * (1.0f / E_DIM) - mu * mu;
    float rstd = rsqrtf(var + 1e-5f);

    float4 gg = reinterpret_cast<const float4*>(g)[t];
    float4 bb = reinterpret_cast<const float4*>(be)[t];
    float y0 = (v0 - mu) * rstd * gg.x + bb.x;
    float y1 = (v1 - mu) * rstd * gg.y + bb.y;
    float y2 = (v2 - mu) * rstd * gg.z + bb.z;
    float y3 = (v3 - mu) * rstd * gg.w + bb.w;
    if (of) {
        float4 o; o.x = y0; o.y = y1; o.z = y2; o.w = y3;
        reinterpret_cast<float4*>(of + (size_t)row * E_DIM)[t] = o;
    }
    if (ob) {
        ushort4 o;
        o.x = f2b(y0); o.y = f2b(y1); o.z = f2b(y2); o.w = f2b(y3);
        reinterpret_cast<ushort4*>(ob + (size_t)row * E_DIM)[t] = o;
    }
}

// LN2 variant: v = hb + p0 + p1 + bias (split-K reduce fused), writes f32 out
__global__ __launch_bounds__(256)
void add_ln_sk(const u16* __restrict__ xa, const u16* __restrict__ p0,
               const u16* __restrict__ p1, const float* __restrict__ bias,
               const float* __restrict__ g, const float* __restrict__ be,
               float* __restrict__ of) {
    const int row = blockIdx.x;
    const int t = threadIdx.x;
    const int lane = t & 63, wave = t >> 6;

    float4 va  = ld4<u16>(xa + (size_t)row * E_DIM, t);
    float4 vp0 = ld4<u16>(p0 + (size_t)row * E_DIM, t);
    float4 vp1 = ld4<u16>(p1 + (size_t)row * E_DIM, t);
    float4 bi = reinterpret_cast<const float4*>(bias)[t];
    float v0 = va.x + vp0.x + vp1.x + bi.x;
    float v1 = va.y + vp0.y + vp1.y + bi.y;
    float v2 = va.z + vp0.z + vp1.z + bi.z;
    float v3 = va.w + vp0.w + vp1.w + bi.w;
    float s  = v0 + v1 + v2 + v3;
    float s2 = v0 * v0 + v1 * v1 + v2 * v2 + v3 * v3;
#pragma unroll
    for (int m = 32; m >= 1; m >>= 1) {
        s  += __shfl_xor(s, m);
        s2 += __shfl_xor(s2, m);
    }
    __shared__ float red[8];
    if (lane == 0) { red[wave] = s; red[4 + wave] = s2; }
    __syncthreads();
    s  = red[0] + red[1] + red[2] + red[3];
    s2 = red[4] + red[5] + red[6] + red[7];

    float mu   = s * (1.0f / E_DIM);
    float var  = s2 * (1.0f / E_DIM) - mu * mu;
    float rstd = rsqrtf(var + 1e-5f);

    float4 gg = reinterpret_cast<const float4*>(g)[t];
    float4 bb = reinterpret_cast<const float4*>(be)[t];
    float4 o;
    o.x = (v0 - mu) * rstd * gg.x + bb.x;
    o.y = (v1 - mu) * rstd * gg.y + bb.y;
    o.z = (v2 - mu) * rstd * gg.z + bb.z;
    o.w = (v3 - mu) * rstd * gg.w + bb.w;
    reinterpret_cast<float4*>(of + (size_t)row * E_DIM)[t] = o;
}

// ---------------- launch ----------------
extern "C" void kernel_launch(void* const* d_in, const int* in_sizes, int n_in,
                              void* d_out, int out_size, void* d_ws, size_t ws_size,
                              hipStream_t stream) {
    const float* x   = (const float*)d_in[0];
    const float* Wq  = (const float*)d_in[1];
    const float* Wk  = (const float*)d_in[2];
    const float* Wv  = (const float*)d_in[3];
    const float* Wo  = (const float*)d_in[4];
    const float* g1  = (const float*)d_in[5];
    const float* b1  = (const float*)d_in[6];
    const float* g2  = (const float*)d_in[7];
    const float* b2  = (const float*)d_in[8];
    const float* W1  = (const float*)d_in[9];
    const float* bb1 = (const float*)d_in[10];
    const float* W2  = (const float*)d_in[11];
    const float* bb2 = (const float*)d_in[12];
    float* out = (float*)d_out;

    char* ws = (char*)d_ws;
    const size_t MB = 1024ull * 1024ull;
    u16* wqkvb = (u16*)(ws + 0 * MB);            // [3072,1024] bf16 = 6MB
    u16* wob   = (u16*)(ws + 6 * MB);
    u16* w1b   = (u16*)(ws + 8 * MB);
    u16* w2b   = (u16*)(ws + 16 * MB);
    u16* xb    = (u16*)(ws + 24 * MB);
    u16* qkvb  = (u16*)(ws + 40 * MB);           // [8192,3072] (V cols unused)
    u16* attnb = (u16*)(ws + 88 * MB);
    u16* attno = (u16*)(ws + 104 * MB);
    u16* hb    = (u16*)(ws + 136 * MB);
    char* VtG  = (ws + 152 * MB);                // [B*H][64 d][4096 B] = 16MB
    u16* ffn1  = (u16*)(ws + 24 * MB);           // reuse xb/qkvb region (after LN1)
    u16* psk   = (u16*)(ws + 168 * MB);          // FFN2 split-K partials: 2 x 16MB

    dim3 blk(256);

    CastArgs ca;
    ca.src[0] = x;   ca.dst[0] = xb;                            ca.scale[0] = 1.f;
    ca.src[1] = Wq;  ca.dst[1] = wqkvb;                         ca.scale[1] = SC_LOG2E;
    ca.src[2] = Wk;  ca.dst[2] = wqkvb + E_DIM * E_DIM;         ca.scale[2] = 1.f;
    ca.src[3] = Wv;  ca.dst[3] = wqkvb + 2 * E_DIM * E_DIM;     ca.scale[3] = 1.f;
    ca.src[4] = Wo;  ca.dst[4] = wob;                           ca.scale[4] = 1.f;
    ca.src[5] = W1;  ca.dst[5] = w1b;                           ca.scale[5] = 1.f;
    ca.src[6] = W2;  ca.dst[6] = w2b;                           ca.scale[6] = 1.f;
    unsigned n4[7] = {M_ROWS * E_DIM / 4, E_DIM * E_DIM / 4, E_DIM * E_DIM / 4,
                      E_DIM * E_DIM / 4, E_DIM * E_DIM / 4, F_DIM * E_DIM / 4,
                      E_DIM * F_DIM / 4};
    ca.cum4[0] = 0;
    for (int i = 0; i < 7; ++i) ca.cum4[i + 1] = ca.cum4[i] + n4[i];
    cast_multi<<<dim3(2048), blk, 0, stream>>>(ca);

    // QKV fused: Q,K -> qkvb ; V -> VtG  (gemm2n: 256x128 tile, 768 blocks)
    gemm2n<u16, false, false, E_DIM, E_DIM, true><<<dim3(QKV_LD / 128, M_ROWS / 256), blk, 0, stream>>>(
        xb, wqkvb, qkvb, nullptr, VtG, M_ROWS, QKV_LD);

    // attn: 1D bh-major grid (512 blocks, 512 thr)
    attn_kernel<<<dim3(512), dim3(512), 0, stream>>>(qkvb, VtG, attnb);

    // Wo: [8192,1024] on gemm2h
    gemm2h<u16, false, false, E_DIM><<<dim3(E_DIM / 128, M_ROWS / 128), blk, 0, stream>>>(
        attnb, wob, attno, nullptr, M_ROWS, E_DIM);

    // LN1: residual uses bf16 x (xb)
    add_ln<u16, u16><<<dim3(M_ROWS), blk, 0, stream>>>(xb, attno, g1, b1, nullptr, hb);

    // FFN1: [8192,4096]  (gemm2n, 1024 blocks)
    gemm2n<u16, true, true, E_DIM, E_DIM, false><<<dim3(F_DIM / 128, M_ROWS / 256), blk, 0, stream>>>(
        hb, w1b, ffn1, bb1, nullptr, M_ROWS, F_DIM);

    // FFN2: [8192,1024] K=4096 split-K x2 (512 blocks, 2/CU)
    gemm2n<u16, false, false, F_DIM, F_DIM / 2, false><<<dim3(E_DIM / 128, M_ROWS / 256, 2), blk, 0, stream>>>(
        ffn1, w2b, psk, nullptr, nullptr, M_ROWS, E_DIM);

    // LN2 with fused split-K reduce + bias
    add_ln_sk<<<dim3(M_ROWS), blk, 0, stream>>>(
        hb, psk, psk + (size_t)M_ROWS * E_DIM, bb2, g2, b2, out);
}